// Round 5
// baseline (230.845 us; speedup 1.0000x reference)
//
#include <hip/hip_runtime.h>
#include <hip/hip_bf16.h>
#include <stdint.h>

typedef __bf16 bf16_t;
typedef __attribute__((ext_vector_type(8))) __bf16 bf16x8;
typedef __attribute__((ext_vector_type(4))) __bf16 bf16x4;
typedef __attribute__((ext_vector_type(16))) float f32x16;

// ---------------------------------------------------------------------------
// q8: exact re-implementation of reference to_float8.
// ---------------------------------------------------------------------------
__device__ __forceinline__ float q8(float v) {
    float a = __builtin_fabsf(v);
    float z = a + 1e-8f;
    int ei = ((__float_as_int(z) >> 23) & 0xff) - 127;
    ei = ei > 7 ? 7 : (ei < -7 ? -7 : ei);
    float p  = __int_as_float((ei + 127) << 23);
    float ip = __int_as_float((127 - ei) << 23);
    float m  = __builtin_fmaf(a, ip, -1.0f);
    float mq = __builtin_rintf(m * 8.0f) * 0.125f;
    float r  = (1.0f + mq) * p;
    return v < 0.0f ? -r : r;
}

__device__ __forceinline__ void gload_lds16(const bf16_t* g, bf16_t* l) {
    __builtin_amdgcn_global_load_lds(
        (__attribute__((address_space(1))) void*)(g),
        (__attribute__((address_space(3))) void*)(l), 16, 0, 0);
}

// ---------------------------------------------------------------------------
// Fused pack kernel, exact 1D grid (20480 blocks).
//   [0, 12288):     XU (4096x3072) = [bf16(x) | bf16(u)], 3 blocks/row
//   [12288, 18432): AB (2048x3072) = [q8(A) | q8(B)],     3 blocks/row
//   [18432, 20480): CQ (1024x2048) = q8(C),               2 blocks/row
// ---------------------------------------------------------------------------
__global__ void pack_all(const float* __restrict__ x, const float* __restrict__ u,
                         const float* __restrict__ A, const float* __restrict__ B,
                         const float* __restrict__ C,
                         bf16_t* __restrict__ XU, bf16_t* __restrict__ AB,
                         bf16_t* __restrict__ CQ) {
    unsigned bid = blockIdx.x;
    if (bid < 12288u) {
        unsigned row = bid / 3u, piece = bid - row * 3u;
        int col = (piece * 256 + threadIdx.x) * 4;
        float4 v;
        if (col < 2048) v = *(const float4*)&x[(size_t)row * 2048 + col];
        else            v = *(const float4*)&u[(size_t)row * 1024 + (col - 2048)];
        bf16x4 o = { (bf16_t)v.x, (bf16_t)v.y, (bf16_t)v.z, (bf16_t)v.w };
        *(bf16x4*)&XU[(size_t)row * 3072 + col] = o;
    } else if (bid < 18432u) {
        unsigned b = bid - 12288u;
        unsigned row = b / 3u, piece = b - row * 3u;
        int col = (piece * 256 + threadIdx.x) * 4;
        float4 v;
        if (col < 2048) v = *(const float4*)&A[(size_t)row * 2048 + col];
        else            v = *(const float4*)&B[(size_t)row * 1024 + (col - 2048)];
        bf16x4 o = { (bf16_t)q8(v.x), (bf16_t)q8(v.y), (bf16_t)q8(v.z), (bf16_t)q8(v.w) };
        *(bf16x4*)&AB[(size_t)row * 3072 + col] = o;
    } else {
        unsigned b = bid - 18432u;
        unsigned row = b >> 1, piece = b & 1u;
        int col = (piece * 256 + threadIdx.x) * 4;
        float4 v = *(const float4*)&C[(size_t)row * 2048 + col];
        bf16x4 o = { (bf16_t)q8(v.x), (bf16_t)q8(v.y), (bf16_t)q8(v.z), (bf16_t)q8(v.w) };
        *(bf16x4*)&CQ[(size_t)row * 2048 + col] = o;
    }
}

// ---------------------------------------------------------------------------
// GEMM (B^T): outf[i,j] = q8( sum_k A[i,k]*B[j,k] ), f32 out, optional bf16
// copy. Round-5 restructure:
//  * v_mfma_f32_32x32x16_bf16, 64x64 wave tile (im2 x in2): 8 B LDS-read per
//    MFMA-lane vs 12 before, at 2x FLOP per MFMA -> 3x FLOP/LDS-byte.
//    (Round-4 analysis: kernel was LDS-read-BW-bound, MfmaUtil capped 36%.)
//  * 256 thr (2x2 waves), block 128x128, BK=64, DOUBLE-buffered LDS (64 KB,
//    still 2 blocks/CU): loads for tile t+1 issued right after the barrier,
//    drained one full compute phase later -> vmcnt drain hidden.
//  * XOR swizzle on global column chunk (c ^ (r&7)): even 4-dword/bank
//    coverage for both staging writes and ds_read_b128 frag reads.
// A-frag: lane reads A[row=strip+(lane&31)][k=(lane>>5)*8 + s*16 .. +7]
// B-frag: same with row = n. C/D: col=lane&31, row=(reg&3)+8*(reg>>2)+4*(lane>>5).
// ---------------------------------------------------------------------------
template<bool DUAL>
__global__ __launch_bounds__(256, 2)
void gemm32_q8(const bf16_t* __restrict__ A, const bf16_t* __restrict__ B,
               float* __restrict__ outf, bf16_t* __restrict__ outb,
               int M, int N, int K) {
    constexpr int BM = 128, BN = 128, BK = 64;
    constexpr int TILE = BM * BK;                 // elements per buffer

    __shared__ alignas(16) bf16_t sA[2][TILE];
    __shared__ alignas(16) bf16_t sB[2][TILE];

    const int tid  = threadIdx.x;
    const int lane = tid & 63;
    const int wave = tid >> 6;       // 0..3
    const int wm   = wave & 1;
    const int wn   = wave >> 1;
    const int ln32 = lane & 31;
    const int hi   = lane >> 5;      // k-group

    const int brow = blockIdx.y * BM;
    const int bcol = blockIdx.x * BN;

    // staging pointers: chunk = it*256+tid -> row r = it*32 + (tid>>3),
    // slot c = tid&7; global column chunk = c ^ (r&7) (XOR swizzle).
    const bf16_t* gA[4]; const bf16_t* gB[4];
#pragma unroll
    for (int it = 0; it < 4; ++it) {
        int r = it * 32 + (tid >> 3);
        int c = (tid & 7) ^ (r & 7);
        gA[it] = A + (size_t)(brow + r) * K + c * 8;
        gB[it] = B + (size_t)(bcol + r) * K + c * 8;
    }

    auto stage = [&](int b) {
#pragma unroll
        for (int it = 0; it < 4; ++it) {
            gload_lds16(gA[it], &sA[b][(it * 256 + wave * 64) * 8]);
            gA[it] += BK;
        }
#pragma unroll
        for (int it = 0; it < 4; ++it) {
            gload_lds16(gB[it], &sB[b][(it * 256 + wave * 64) * 8]);
            gB[it] += BK;
        }
    };

    // fragment LDS offsets (elements): row r, k-chunk cg = s*2 + hi
    int a_off[2][4], b_off[2][4];
#pragma unroll
    for (int im = 0; im < 2; ++im) {
        int r = wm * 64 + im * 32 + ln32;
#pragma unroll
        for (int s = 0; s < 4; ++s) {
            int cg = s * 2 + hi;
            a_off[im][s] = (r * 8 + (cg ^ (r & 7))) * 8;
        }
    }
#pragma unroll
    for (int in = 0; in < 2; ++in) {
        int r = wn * 64 + in * 32 + ln32;
#pragma unroll
        for (int s = 0; s < 4; ++s) {
            int cg = s * 2 + hi;
            b_off[in][s] = (r * 8 + (cg ^ (r & 7))) * 8;
        }
    }

    f32x16 acc[2][2];
#pragma unroll
    for (int im = 0; im < 2; ++im)
#pragma unroll
        for (int in = 0; in < 2; ++in)
            acc[im][in] = (f32x16)(0.0f);

    auto compute = [&](int b) {
#pragma unroll
        for (int s = 0; s < 4; ++s) {
            bf16x8 af[2], bfv[2];
#pragma unroll
            for (int im = 0; im < 2; ++im) af[im]  = *(const bf16x8*)(&sA[b][a_off[im][s]]);
#pragma unroll
            for (int in = 0; in < 2; ++in) bfv[in] = *(const bf16x8*)(&sB[b][b_off[in][s]]);
#pragma unroll
            for (int im = 0; im < 2; ++im)
#pragma unroll
                for (int in = 0; in < 2; ++in)
                    acc[im][in] = __builtin_amdgcn_mfma_f32_32x32x16_bf16(
                        af[im], bfv[in], acc[im][in], 0, 0, 0);
        }
    };

    const int T = K / BK;            // 48 (GEMM1) / 32 (GEMM2): even
    stage(0);
    for (int t = 0; t < T; t += 2) {
        __syncthreads();             // drains tile-t loads (issued 1 phase ago)
        stage(1);                    // t+1 <= T-1 always (T even)
        compute(0);
        __syncthreads();             // drains tile-(t+1) loads
        if (t + 2 < T) stage(0);
        compute(1);
    }

    // epilogue
#pragma unroll
    for (int im = 0; im < 2; ++im) {
#pragma unroll
        for (int in = 0; in < 2; ++in) {
            int gn = bcol + wn * 64 + in * 32 + ln32;
#pragma unroll
            for (int reg = 0; reg < 16; ++reg) {
                int row = (reg & 3) + 8 * (reg >> 2) + 4 * hi;
                int gm = brow + wm * 64 + im * 32 + row;
                float v = q8(acc[im][in][reg]);
                outf[(size_t)gm * N + gn] = v;
                if (DUAL) outb[(size_t)gm * N + gn] = (bf16_t)v;
            }
        }
    }
}

// ---------------------------------------------------------------------------
extern "C" void kernel_launch(void* const* d_in, const int* in_sizes, int n_in,
                              void* d_out, int out_size, void* d_ws, size_t ws_size,
                              hipStream_t stream) {
    const float* x = (const float*)d_in[0];   // 4096 x 2048
    const float* u = (const float*)d_in[1];   // 4096 x 1024
    const float* A = (const float*)d_in[2];   // 2048 x 2048
    const float* B = (const float*)d_in[3];   // 2048 x 1024
    const float* C = (const float*)d_in[4];   // 1024 x 2048

    float* outf = (float*)d_out;
    float* xnf  = outf;                                 // 4096 x 2048 f32
    float* yf   = outf + (size_t)4096 * 2048;           // 4096 x 1024 f32

    uint8_t* ws = (uint8_t*)d_ws;
    bf16_t* XU = (bf16_t*)ws;                                            // 24 MB
    bf16_t* AB = (bf16_t*)(ws + (size_t)25165824);                       // 12 MB
    bf16_t* CQ = (bf16_t*)(ws + (size_t)25165824 + 12582912);            //  4 MB
    bf16_t* XN = (bf16_t*)(ws + (size_t)25165824 + 12582912 + 4194304);  // 16 MB

    pack_all<<<dim3(20480), 256, 0, stream>>>(x, u, A, B, C, XU, AB, CQ);

    // x_next = q8([x|u] @ [Aq|Bq]^T): M=4096 N=2048 K=3072; dual f32+bf16 out
    gemm32_q8<true><<<dim3(2048 / 128, 4096 / 128), 256, 0, stream>>>(
        XU, AB, xnf, XN, 4096, 2048, 3072);
    // y = q8(x_next @ Cq^T): M=4096 N=1024 K=2048 (XN bf16 copy is exact)
    gemm32_q8<false><<<dim3(1024 / 128, 4096 / 128), 256, 0, stream>>>(
        XN, CQ, yf, nullptr, 4096, 1024, 2048);
}

// Round 6
// 210.384 us; speedup vs baseline: 1.0973x; 1.0973x over previous
//
#include <hip/hip_runtime.h>
#include <hip/hip_bf16.h>
#include <stdint.h>

typedef __bf16 bf16_t;
typedef __attribute__((ext_vector_type(8))) __bf16 bf16x8;
typedef __attribute__((ext_vector_type(4))) __bf16 bf16x4;
typedef __attribute__((ext_vector_type(4))) float f32x4;

// ---------------------------------------------------------------------------
// q8: exact re-implementation of reference to_float8.
// ---------------------------------------------------------------------------
__device__ __forceinline__ float q8(float v) {
    float a = __builtin_fabsf(v);
    float z = a + 1e-8f;
    int ei = ((__float_as_int(z) >> 23) & 0xff) - 127;
    ei = ei > 7 ? 7 : (ei < -7 ? -7 : ei);
    float p  = __int_as_float((ei + 127) << 23);
    float ip = __int_as_float((127 - ei) << 23);
    float m  = __builtin_fmaf(a, ip, -1.0f);
    float mq = __builtin_rintf(m * 8.0f) * 0.125f;
    float r  = (1.0f + mq) * p;
    return v < 0.0f ? -r : r;
}

__device__ __forceinline__ void gload_lds16(const bf16_t* g, bf16_t* l) {
    __builtin_amdgcn_global_load_lds(
        (__attribute__((address_space(1))) void*)(g),
        (__attribute__((address_space(3))) void*)(l), 16, 0, 0);
}

// ---------------------------------------------------------------------------
// Fused pack kernel, exact 1D grid (20480 blocks).
//   [0, 12288):     XU (4096x3072) = [bf16(x) | bf16(u)], 3 blocks/row
//   [12288, 18432): AB (2048x3072) = [q8(A) | q8(B)],     3 blocks/row
//   [18432, 20480): CQ (1024x2048) = q8(C),               2 blocks/row
// ---------------------------------------------------------------------------
__global__ void pack_all(const float* __restrict__ x, const float* __restrict__ u,
                         const float* __restrict__ A, const float* __restrict__ B,
                         const float* __restrict__ C,
                         bf16_t* __restrict__ XU, bf16_t* __restrict__ AB,
                         bf16_t* __restrict__ CQ) {
    unsigned bid = blockIdx.x;
    if (bid < 12288u) {
        unsigned row = bid / 3u, piece = bid - row * 3u;
        int col = (piece * 256 + threadIdx.x) * 4;
        float4 v;
        if (col < 2048) v = *(const float4*)&x[(size_t)row * 2048 + col];
        else            v = *(const float4*)&u[(size_t)row * 1024 + (col - 2048)];
        bf16x4 o = { (bf16_t)v.x, (bf16_t)v.y, (bf16_t)v.z, (bf16_t)v.w };
        *(bf16x4*)&XU[(size_t)row * 3072 + col] = o;
    } else if (bid < 18432u) {
        unsigned b = bid - 12288u;
        unsigned row = b / 3u, piece = b - row * 3u;
        int col = (piece * 256 + threadIdx.x) * 4;
        float4 v;
        if (col < 2048) v = *(const float4*)&A[(size_t)row * 2048 + col];
        else            v = *(const float4*)&B[(size_t)row * 1024 + (col - 2048)];
        bf16x4 o = { (bf16_t)q8(v.x), (bf16_t)q8(v.y), (bf16_t)q8(v.z), (bf16_t)q8(v.w) };
        *(bf16x4*)&AB[(size_t)row * 3072 + col] = o;
    } else {
        unsigned b = bid - 18432u;
        unsigned row = b >> 1, piece = b & 1u;
        int col = (piece * 256 + threadIdx.x) * 4;
        float4 v = *(const float4*)&C[(size_t)row * 2048 + col];
        bf16x4 o = { (bf16_t)q8(v.x), (bf16_t)q8(v.y), (bf16_t)q8(v.z), (bf16_t)q8(v.w) };
        *(bf16x4*)&CQ[(size_t)row * 2048 + col] = o;
    }
}

// ---------------------------------------------------------------------------
// GEMM (B^T): outf[i,j] = q8( sum_k A[i,k]*B[j,k] ), f32 out, optional bf16
// copy. Round-6 = round-3/4 verified structure + double-buffered LDS:
//  * 512 threads (8 waves, wm=wave&3 x wn=wave>>2), 128 x BN tile, BK=64.
//    Grid = 2 blocks/CU (grid-capped) -> 16 waves/CU. [round 5 showed
//    8 waves/CU loses ~20% regardless of FLOP/LDS-byte ratio]
//  * 16x16x32 MFMA with the swizzle verified conflict-free in rounds 2-4
//    (slot c ^ (r&7); SQ_LDS_BANK_CONFLICT == 0 measured).
//  * DOUBLE-buffered LDS (2 x 32 KB for BN=128 -> 64 KB, keeps 2 blocks/CU):
//    stage(next) issued right after each barrier, drained one full compute
//    phase (16 MFMAs/wave) later -> the per-iter vmcnt(0) drain that capped
//    rounds 3/4 at 32-36% MfmaUtil is overlapped instead of amortized.
// ---------------------------------------------------------------------------
template<int BN, bool DUAL>
__global__ __launch_bounds__(512, 4)
void gemm_q8_kernel(const bf16_t* __restrict__ A, const bf16_t* __restrict__ B,
                    float* __restrict__ outf, bf16_t* __restrict__ outb,
                    int M, int N, int K) {
    constexpr int BM = 128;
    constexpr int BK = 64;                           // 8 chunks of 8 elems per row
    constexpr int NI = BN / 32;
    constexpr int A_ITS = BM * (BK / 8) / 512;       // 2
    constexpr int B_ITS = BN * (BK / 8) / 512;       // 2 (BN=128) / 1 (BN=64)

    __shared__ alignas(16) bf16_t sA[2][BM * BK];
    __shared__ alignas(16) bf16_t sB[2][BN * BK];

    const int tid  = threadIdx.x;
    const int lane = tid & 63;
    const int wave = tid >> 6;       // 0..7
    const int wm   = wave & 3;       // 4 m-strips of 32 rows
    const int wn   = wave >> 2;      // 2 n-strips of BN/2
    const int ln16 = lane & 15;
    const int quad = lane >> 4;

    const int brow = blockIdx.y * BM;
    const int bcol = blockIdx.x * BN;

    // staging: LDS lane-linear slots, global column chunk XOR-permuted
    const bf16_t* gA[A_ITS];
#pragma unroll
    for (int it = 0; it < A_ITS; ++it) {
        int L = it * 512 + tid;
        int r = L >> 3, c = L & 7;
        gA[it] = A + (size_t)(brow + r) * K + (c ^ (r & 7)) * 8;
    }
    const bf16_t* gB[B_ITS];
#pragma unroll
    for (int it = 0; it < B_ITS; ++it) {
        int L = it * 512 + tid;
        int r = L >> 3, c = L & 7;
        gB[it] = B + (size_t)(bcol + r) * K + (c ^ (r & 7)) * 8;
    }

    auto stage = [&](int b) {
#pragma unroll
        for (int it = 0; it < A_ITS; ++it) {
            gload_lds16(gA[it], &sA[b][(it * 512 + wave * 64) * 8]);
            gA[it] += BK;
        }
#pragma unroll
        for (int it = 0; it < B_ITS; ++it) {
            gload_lds16(gB[it], &sB[b][(it * 512 + wave * 64) * 8]);
            gB[it] += BK;
        }
    };

    // loop-invariant fragment LDS offsets (elements), s = K-substep (0..1)
    int a_off[2][2], b_off[NI][2];
#pragma unroll
    for (int im = 0; im < 2; ++im) {
        int r = wm * 32 + im * 16 + ln16;
#pragma unroll
        for (int s = 0; s < 2; ++s) {
            int cg = s * 4 + quad;
            a_off[im][s] = (r * 8 + (cg ^ (r & 7))) * 8;
        }
    }
#pragma unroll
    for (int in = 0; in < NI; ++in) {
        int r = wn * (BN / 2) + in * 16 + ln16;
#pragma unroll
        for (int s = 0; s < 2; ++s) {
            int cg = s * 4 + quad;
            b_off[in][s] = (r * 8 + (cg ^ (r & 7))) * 8;
        }
    }

    f32x4 acc[2][NI];
#pragma unroll
    for (int im = 0; im < 2; ++im)
#pragma unroll
        for (int in = 0; in < NI; ++in)
            acc[im][in] = (f32x4){0.f, 0.f, 0.f, 0.f};

    auto compute = [&](int b) {
#pragma unroll
        for (int s = 0; s < 2; ++s) {
            bf16x8 af[2], bfv[NI];
#pragma unroll
            for (int im = 0; im < 2; ++im) af[im]  = *(const bf16x8*)(&sA[b][a_off[im][s]]);
#pragma unroll
            for (int in = 0; in < NI; ++in) bfv[in] = *(const bf16x8*)(&sB[b][b_off[in][s]]);
#pragma unroll
            for (int im = 0; im < 2; ++im)
#pragma unroll
                for (int in = 0; in < NI; ++in)
                    acc[im][in] = __builtin_amdgcn_mfma_f32_16x16x32_bf16(
                        af[im], bfv[in], acc[im][in], 0, 0, 0);
        }
    };

    const int T = K / BK;            // 48 (GEMM1) / 32 (GEMM2): even
    stage(0);
    for (int t = 0; t < T; t += 2) {
        __syncthreads();             // drains buf0 loads (issued 1 phase ago)
        stage(1);                    // t+1 <= T-1 (T even)
        compute(0);
        __syncthreads();             // drains buf1 loads
        if (t + 2 < T) stage(0);
        compute(1);
    }

    // epilogue: C/D layout col = lane&15, row = quad*4 + reg
    const int rbase = quad * 4;
#pragma unroll
    for (int im = 0; im < 2; ++im) {
#pragma unroll
        for (int in = 0; in < NI; ++in) {
            int gm = brow + wm * 32 + im * 16 + rbase;
            int gn = bcol + wn * (BN / 2) + in * 16 + ln16;
#pragma unroll
            for (int r = 0; r < 4; ++r) {
                float v = q8(acc[im][in][r]);
                outf[(size_t)(gm + r) * N + gn] = v;
                if (DUAL) outb[(size_t)(gm + r) * N + gn] = (bf16_t)v;
            }
        }
    }
}

// ---------------------------------------------------------------------------
extern "C" void kernel_launch(void* const* d_in, const int* in_sizes, int n_in,
                              void* d_out, int out_size, void* d_ws, size_t ws_size,
                              hipStream_t stream) {
    const float* x = (const float*)d_in[0];   // 4096 x 2048
    const float* u = (const float*)d_in[1];   // 4096 x 1024
    const float* A = (const float*)d_in[2];   // 2048 x 2048
    const float* B = (const float*)d_in[3];   // 2048 x 1024
    const float* C = (const float*)d_in[4];   // 1024 x 2048

    float* outf = (float*)d_out;
    float* xnf  = outf;                                 // 4096 x 2048 f32
    float* yf   = outf + (size_t)4096 * 2048;           // 4096 x 1024 f32

    uint8_t* ws = (uint8_t*)d_ws;
    bf16_t* XU = (bf16_t*)ws;                                            // 24 MB
    bf16_t* AB = (bf16_t*)(ws + (size_t)25165824);                       // 12 MB
    bf16_t* CQ = (bf16_t*)(ws + (size_t)25165824 + 12582912);            //  4 MB
    bf16_t* XN = (bf16_t*)(ws + (size_t)25165824 + 12582912 + 4194304);  // 16 MB

    pack_all<<<dim3(20480), 256, 0, stream>>>(x, u, A, B, C, XU, AB, CQ);

    // x_next = q8([x|u] @ [Aq|Bq]^T): M=4096 N=2048 K=3072; dual f32+bf16 out
    gemm_q8_kernel<128, true><<<dim3(2048 / 128, 4096 / 128), 512, 0, stream>>>(
        XU, AB, xnf, XN, 4096, 2048, 3072);
    // y = q8(x_next @ Cq^T): M=4096 N=1024 K=2048 (XN bf16 copy is exact)
    gemm_q8_kernel<64, false><<<dim3(1024 / 64, 4096 / 128), 512, 0, stream>>>(
        XN, CQ, yf, nullptr, 4096, 1024, 2048);
}

// Round 7
// 201.126 us; speedup vs baseline: 1.1478x; 1.0460x over previous
//
#include <hip/hip_runtime.h>
#include <hip/hip_bf16.h>
#include <stdint.h>

typedef __bf16 bf16_t;
typedef __attribute__((ext_vector_type(8))) __bf16 bf16x8;
typedef __attribute__((ext_vector_type(4))) __bf16 bf16x4;
typedef __attribute__((ext_vector_type(4))) float f32x4;

// ---------------------------------------------------------------------------
// q8: exact re-implementation of reference to_float8.
// ---------------------------------------------------------------------------
__device__ __forceinline__ float q8(float v) {
    float a = __builtin_fabsf(v);
    float z = a + 1e-8f;
    int ei = ((__float_as_int(z) >> 23) & 0xff) - 127;
    ei = ei > 7 ? 7 : (ei < -7 ? -7 : ei);
    float p  = __int_as_float((ei + 127) << 23);
    float ip = __int_as_float((127 - ei) << 23);
    float m  = __builtin_fmaf(a, ip, -1.0f);
    float mq = __builtin_rintf(m * 8.0f) * 0.125f;
    float r  = (1.0f + mq) * p;
    return v < 0.0f ? -r : r;
}

__device__ __forceinline__ void gload_lds16(const bf16_t* g, bf16_t* l) {
    __builtin_amdgcn_global_load_lds(
        (__attribute__((address_space(1))) void*)(g),
        (__attribute__((address_space(3))) void*)(l), 16, 0, 0);
}

// ---------------------------------------------------------------------------
// Fused pack kernel, exact 1D grid (20480 blocks).
//   [0, 12288):     XU (4096x3072) = [bf16(x) | bf16(u)], 3 blocks/row
//   [12288, 18432): AB (2048x3072) = [q8(A) | q8(B)],     3 blocks/row
//   [18432, 20480): CQ (1024x2048) = q8(C),               2 blocks/row
// ---------------------------------------------------------------------------
__global__ void pack_all(const float* __restrict__ x, const float* __restrict__ u,
                         const float* __restrict__ A, const float* __restrict__ B,
                         const float* __restrict__ C,
                         bf16_t* __restrict__ XU, bf16_t* __restrict__ AB,
                         bf16_t* __restrict__ CQ) {
    unsigned bid = blockIdx.x;
    if (bid < 12288u) {
        unsigned row = bid / 3u, piece = bid - row * 3u;
        int col = (piece * 256 + threadIdx.x) * 4;
        float4 v;
        if (col < 2048) v = *(const float4*)&x[(size_t)row * 2048 + col];
        else            v = *(const float4*)&u[(size_t)row * 1024 + (col - 2048)];
        bf16x4 o = { (bf16_t)v.x, (bf16_t)v.y, (bf16_t)v.z, (bf16_t)v.w };
        *(bf16x4*)&XU[(size_t)row * 3072 + col] = o;
    } else if (bid < 18432u) {
        unsigned b = bid - 12288u;
        unsigned row = b / 3u, piece = b - row * 3u;
        int col = (piece * 256 + threadIdx.x) * 4;
        float4 v;
        if (col < 2048) v = *(const float4*)&A[(size_t)row * 2048 + col];
        else            v = *(const float4*)&B[(size_t)row * 1024 + (col - 2048)];
        bf16x4 o = { (bf16_t)q8(v.x), (bf16_t)q8(v.y), (bf16_t)q8(v.z), (bf16_t)q8(v.w) };
        *(bf16x4*)&AB[(size_t)row * 3072 + col] = o;
    } else {
        unsigned b = bid - 18432u;
        unsigned row = b >> 1, piece = b & 1u;
        int col = (piece * 256 + threadIdx.x) * 4;
        float4 v = *(const float4*)&C[(size_t)row * 2048 + col];
        bf16x4 o = { (bf16_t)q8(v.x), (bf16_t)q8(v.y), (bf16_t)q8(v.z), (bf16_t)q8(v.w) };
        *(bf16x4*)&CQ[(size_t)row * 2048 + col] = o;
    }
}

// ---------------------------------------------------------------------------
// GEMM (B^T): outf[i,j] = q8( sum_k A[i,k]*B[j,k] ), f32 out, optional bf16
// copy. Round-7 = round-4 verified config (best measured: 60 us, MfmaUtil 36%,
// conflicts 0) + XCD-aware block swizzle:
//  * 128 x BN tile, BK=128, 512 threads (8 waves, 4x2), single-buffer LDS,
//    two barriers per 128-wide K-tile, 16x16x32 MFMA, c^(r&15) XOR swizzle.
//  * NEW: 1D grid of 512, decoded so each XCD (assumed b&7 round-robin) owns
//    an 8x8 patch of the 16x32 block grid: per-XCD L2 working set drops from
//    ~36 MB (scatter) to 12.6 MB (8 A-strips + 8 B-strips). Round-6 FETCH was
//    104 MB vs 36 MB unique -> L2 thrash; the kernel is drain-latency-bound,
//    so L2-hit latency (~200cy) vs L3 (~500+cy) directly shortens the stall.
//    Both GEMM grids are exactly 16x32, one decode serves both.
// ---------------------------------------------------------------------------
template<int BN, bool DUAL>
__global__ __launch_bounds__(512, 4)
void gemm_q8_kernel(const bf16_t* __restrict__ A, const bf16_t* __restrict__ B,
                    float* __restrict__ outf, bf16_t* __restrict__ outb,
                    int M, int N, int K) {
    constexpr int BM = 128;
    constexpr int BK = 128;                        // 16 chunks of 8 elems per row
    constexpr int NI = BN / 32;
    constexpr int A_ITS = BM * (BK / 8) / 512;     // 4
    constexpr int B_ITS = BN * (BK / 8) / 512;     // 4 (BN=128) / 2 (BN=64)

    __shared__ alignas(16) bf16_t sA[BM * BK];
    __shared__ alignas(16) bf16_t sB[BN * BK];

    const int tid  = threadIdx.x;
    const int lane = tid & 63;
    const int wave = tid >> 6;       // 0..7
    const int wm   = wave & 3;       // 4 m-strips of 32 rows
    const int wn   = wave >> 2;      // 2 n-strips of BN/2
    const int ln16 = lane & 15;
    const int quad = lane >> 4;

    // XCD patch swizzle: grid = 512 linear; xcd = b&7 gets 8x8 patch of (x,y)
    const int b   = blockIdx.x;
    const int xcd = b & 7;
    const int g   = b >> 3;                        // 0..63
    const int bx  = (xcd & 1) * 8 + (g & 7);       // 0..15
    const int by  = (xcd >> 1) * 8 + (g >> 3);     // 0..31
    const int brow = by * BM;
    const int bcol = bx * BN;

    // staging: LDS lane-linear slots, global column chunk XOR-permuted
    const bf16_t* gA[A_ITS];
#pragma unroll
    for (int it = 0; it < A_ITS; ++it) {
        int L = it * 512 + tid;
        int r = L >> 4, c = L & 15;
        gA[it] = A + (size_t)(brow + r) * K + (c ^ (r & 15)) * 8;
    }
    const bf16_t* gB[B_ITS];
#pragma unroll
    for (int it = 0; it < B_ITS; ++it) {
        int L = it * 512 + tid;
        int r = L >> 4, c = L & 15;
        gB[it] = B + (size_t)(bcol + r) * K + (c ^ (r & 15)) * 8;
    }

    // loop-invariant fragment LDS offsets (elements), s = K-substep (0..3)
    int a_off[2][4], b_off[NI][4];
#pragma unroll
    for (int im = 0; im < 2; ++im) {
        int r = wm * 32 + im * 16 + ln16;
#pragma unroll
        for (int s = 0; s < 4; ++s) {
            int cg = s * 4 + quad;
            a_off[im][s] = (r * 16 + (cg ^ (r & 15))) * 8;
        }
    }
#pragma unroll
    for (int in = 0; in < NI; ++in) {
        int r = wn * (BN / 2) + in * 16 + ln16;
#pragma unroll
        for (int s = 0; s < 4; ++s) {
            int cg = s * 4 + quad;
            b_off[in][s] = (r * 16 + (cg ^ (r & 15))) * 8;
        }
    }

    f32x4 acc[2][NI];
#pragma unroll
    for (int im = 0; im < 2; ++im)
#pragma unroll
        for (int in = 0; in < NI; ++in)
            acc[im][in] = (f32x4){0.f, 0.f, 0.f, 0.f};

    for (int kt = 0; kt < K; kt += BK) {
#pragma unroll
        for (int it = 0; it < A_ITS; ++it) {
            gload_lds16(gA[it], sA + (it * 512 + wave * 64) * 8);
            gA[it] += BK;
        }
#pragma unroll
        for (int it = 0; it < B_ITS; ++it) {
            gload_lds16(gB[it], sB + (it * 512 + wave * 64) * 8);
            gB[it] += BK;
        }
        __syncthreads();   // drains vmcnt of async LDS stores + barrier
#pragma unroll
        for (int s = 0; s < 4; ++s) {
            bf16x8 af[2], bfv[NI];
#pragma unroll
            for (int im = 0; im < 2; ++im) af[im]  = *(const bf16x8*)(sA + a_off[im][s]);
#pragma unroll
            for (int in = 0; in < NI; ++in) bfv[in] = *(const bf16x8*)(sB + b_off[in][s]);
#pragma unroll
            for (int im = 0; im < 2; ++im)
#pragma unroll
                for (int in = 0; in < NI; ++in)
                    acc[im][in] = __builtin_amdgcn_mfma_f32_16x16x32_bf16(
                        af[im], bfv[in], acc[im][in], 0, 0, 0);
        }
        __syncthreads();
    }

    // epilogue: C/D layout col = lane&15, row = quad*4 + reg
    const int rbase = quad * 4;
#pragma unroll
    for (int im = 0; im < 2; ++im) {
#pragma unroll
        for (int in = 0; in < NI; ++in) {
            int gm = brow + wm * 32 + im * 16 + rbase;
            int gn = bcol + wn * (BN / 2) + in * 16 + ln16;
#pragma unroll
            for (int r = 0; r < 4; ++r) {
                float v = q8(acc[im][in][r]);
                outf[(size_t)(gm + r) * N + gn] = v;
                if (DUAL) outb[(size_t)(gm + r) * N + gn] = (bf16_t)v;
            }
        }
    }
}

// ---------------------------------------------------------------------------
extern "C" void kernel_launch(void* const* d_in, const int* in_sizes, int n_in,
                              void* d_out, int out_size, void* d_ws, size_t ws_size,
                              hipStream_t stream) {
    const float* x = (const float*)d_in[0];   // 4096 x 2048
    const float* u = (const float*)d_in[1];   // 4096 x 1024
    const float* A = (const float*)d_in[2];   // 2048 x 2048
    const float* B = (const float*)d_in[3];   // 2048 x 1024
    const float* C = (const float*)d_in[4];   // 1024 x 2048

    float* outf = (float*)d_out;
    float* xnf  = outf;                                 // 4096 x 2048 f32
    float* yf   = outf + (size_t)4096 * 2048;           // 4096 x 1024 f32

    uint8_t* ws = (uint8_t*)d_ws;
    bf16_t* XU = (bf16_t*)ws;                                            // 24 MB
    bf16_t* AB = (bf16_t*)(ws + (size_t)25165824);                       // 12 MB
    bf16_t* CQ = (bf16_t*)(ws + (size_t)25165824 + 12582912);            //  4 MB
    bf16_t* XN = (bf16_t*)(ws + (size_t)25165824 + 12582912 + 4194304);  // 16 MB

    pack_all<<<dim3(20480), 256, 0, stream>>>(x, u, A, B, C, XU, AB, CQ);

    // x_next = q8([x|u] @ [Aq|Bq]^T): M=4096 N=2048 K=3072; dual f32+bf16 out
    // grid 16x32 = 512, 1D with XCD patch decode
    gemm_q8_kernel<128, true><<<dim3(512), 512, 0, stream>>>(
        XU, AB, xnf, XN, 4096, 2048, 3072);
    // y = q8(x_next @ Cq^T): M=4096 N=1024 K=2048; grid 16x32 = 512
    gemm_q8_kernel<64, false><<<dim3(512), 512, 0, stream>>>(
        XN, CQ, yf, nullptr, 4096, 1024, 2048);
}